// Round 3
// baseline (780.130 us; speedup 1.0000x reference)
//
#include <hip/hip_runtime.h>

typedef __attribute__((ext_vector_type(8))) short sh8;       // 8 bf16 (4 VGPRs)
typedef __attribute__((ext_vector_type(4))) float f32x4;

#define E_EDGES 100000
#define E_PAD   100096   // 391 * 256
#define N_NODES 20000

#define BAR() do { __builtin_amdgcn_sched_barrier(0); __builtin_amdgcn_s_barrier(); __builtin_amdgcn_sched_barrier(0); } while (0)
#define WAITV0()    asm volatile("s_waitcnt vmcnt(0)" ::: "memory")
#define WAITLGKM0() asm volatile("s_waitcnt lgkmcnt(0)" ::: "memory")

__device__ __forceinline__ unsigned short f2bf(float f) {
  union { float f; unsigned int u; } v; v.f = f;
  unsigned int r = v.u + 0x7FFFu + ((v.u >> 16) & 1u);   // RNE
  return (unsigned short)(r >> 16);
}

__device__ __forceinline__ void async16(const void* g, void* l) {
  __builtin_amdgcn_global_load_lds((const __attribute__((address_space(1))) unsigned int*)g,
                                   (__attribute__((address_space(3))) unsigned int*)l,
                                   16, 0, 0);
}

// ---- w2 (f32 [1024][1024] k-major) -> w2t (bf16 [n][k]) ----
__global__ void transpose_w2_kernel(const float* __restrict__ w2, unsigned short* __restrict__ w2t) {
  __shared__ float tile[32][33];
  int b = blockIdx.x;
  int bx = b & 31, by = b >> 5;
  int lx = threadIdx.x & 31, ly = threadIdx.x >> 5;
#pragma unroll
  for (int j = 0; j < 4; ++j)
    tile[ly + j*8][lx] = w2[(by*32 + ly + j*8)*1024 + bx*32 + lx];
  __syncthreads();
#pragma unroll
  for (int j = 0; j < 4; ++j)
    w2t[(size_t)(bx*32 + ly + j*8)*1024 + by*32 + lx] = f2bf(tile[lx][ly + j*8]);
}

// ---- h1 = relu(ea @ w1 + b1) -> bf16 [E_PAD][1024]; 8 edges per block ----
__global__ __launch_bounds__(256)
void edge_mlp1_kernel(const float* __restrict__ ea, const float* __restrict__ w1,
                      const float* __restrict__ b1, unsigned short* __restrict__ h1) {
  __shared__ float eas[8][16];
  const int tid = threadIdx.x;
  const int e0 = blockIdx.x * 8;
  if (tid < 128) {
    int g = tid >> 4, d = tid & 15;
    int ge = e0 + g;
    eas[g][d] = (ge < E_EDGES) ? ea[(size_t)ge*16 + d] : 0.f;
  }
  __syncthreads();
  const int c0 = tid * 4;
  float4 bb = *(const float4*)(b1 + c0);
  float4 acc[8];
#pragma unroll
  for (int g = 0; g < 8; ++g) acc[g] = bb;
#pragma unroll
  for (int d = 0; d < 16; ++d) {
    float4 w = *(const float4*)(w1 + (size_t)d*1024 + c0);
#pragma unroll
    for (int g = 0; g < 8; ++g) {
      float ev = eas[g][d];
      acc[g].x += ev*w.x; acc[g].y += ev*w.y; acc[g].z += ev*w.z; acc[g].w += ev*w.w;
    }
  }
#pragma unroll
  for (int g = 0; g < 8; ++g) {
    ushort4 o;
    if (e0 + g < E_EDGES) {
      o.x = f2bf(fmaxf(acc[g].x, 0.f)); o.y = f2bf(fmaxf(acc[g].y, 0.f));
      o.z = f2bf(fmaxf(acc[g].z, 0.f)); o.w = f2bf(fmaxf(acc[g].w, 0.f));
    } else {
      o.x = o.y = o.z = o.w = 0;
    }
    *(ushort4*)(h1 + (size_t)(e0 + g)*1024 + c0) = o;
  }
}

// ---- cnt[dst] += 1 ----
__global__ void count_kernel(const int* __restrict__ dst, float* __restrict__ cnt) {
  int t = blockIdx.x*256 + threadIdx.x;
  if (t < E_EDGES) atomicAdd(&cnt[dst[t]], 1.0f);
}

// ==== 256x256x(BK=64) bf16 MFMA GEMM, swizzled LDS, depth-1 prefetch, fused scatter ====
__global__ __launch_bounds__(512, 2)
void gemm_scatter_kernel(const unsigned short* __restrict__ h1,
                         const unsigned short* __restrict__ w2t,
                         const float* __restrict__ b2,
                         const float* __restrict__ xin,
                         const int* __restrict__ src,
                         const int* __restrict__ dst,
                         float* __restrict__ agg) {
  // 128 KiB total static LDS. Epilogue data aliases the (dead) staging bufs.
  __shared__ __align__(16) unsigned short Als[2][256*64];   // 64 KB  [row][k] swizzled
  __shared__ __align__(16) unsigned short Bls[2][256*64];   // 64 KB  [col][k] swizzled
  float* msgA = (float*)&Als[0][0];                          // [256][33] f32 = 33.8 KB
  float* msgB = (float*)&Bls[0][0];                          // [256][33] f32
  float (*xg)[8] = (float (*)[8])((char*)&Als[0][0] + 36864);// 8 KB (inside Als[1], past msgA)
  int* dsts = (int*)((char*)&Bls[0][0] + 36864);             // 1 KB

  const int tid  = threadIdx.x;
  const int wave = tid >> 6, lane = tid & 63;
  const int wm = wave >> 2, wn = wave & 3;                   // 2 x 4 waves, 128x64 each
  const int lr = lane >> 4, lc = lane & 15;

  // bijective XCD swizzle: nwg=1564, q=195, r=4; n-tiles innermost for L2 A-panel reuse
  const int bid = blockIdx.x;
  const int xcd = bid & 7, idx = bid >> 3;
  const int logical = (xcd < 4 ? xcd*196 : 784 + (xcd - 4)*195) + idx;
  const int tile_m = logical >> 2, tile_n = logical & 3;
  const int e0 = tile_m*256, n0 = tile_n*256;

  const unsigned short* Ag = h1  + (size_t)e0*1024;
  const unsigned short* Bg = w2t + (size_t)n0*1024;

  // staging geometry: chunk (wave,j) -> LDS rows (wave*4+j)*8 .. +7, lane covers 16B
  const int rj     = lane >> 3;                    // row within 8-row group
  const int colswz = 8*((lane & 7) ^ rj);          // pre-swizzled source col (elements)
  const int swzb   = (lc & 7) << 4;                // read-side byte XOR

#define STAGE(buf, kt) do {                                                         \
    _Pragma("unroll")                                                               \
    for (int j = 0; j < 4; ++j) {                                                   \
      int row = (wave*4 + j)*8 + rj;                                                \
      async16(Ag + (size_t)row*1024 + (kt)*64 + colswz, &Als[buf][(wave*4 + j)*512]); \
      async16(Bg + (size_t)row*1024 + (kt)*64 + colswz, &Bls[buf][(wave*4 + j)*512]); \
    }                                                                               \
  } while (0)

  f32x4 acc[8][4];
#pragma unroll
  for (int m = 0; m < 8; ++m)
#pragma unroll
    for (int n = 0; n < 4; ++n) acc[m][n] = (f32x4){0.f, 0.f, 0.f, 0.f};

  STAGE(0, 0);

#pragma unroll
  for (int kt = 0; kt < 16; ++kt) {
    const int cur = kt & 1;
    WAITV0();                     // tile kt landed (this wave's loads)
    BAR();                        // all waves: tile kt fully in LDS
    const char* Ab = (const char*)&Als[cur][0];
    const char* Bb = (const char*)&Bls[cur][0];
    sh8 b[4][2], a[8][2];
#pragma unroll
    for (int n = 0; n < 4; ++n)
#pragma unroll
      for (int kk = 0; kk < 2; ++kk)
        b[n][kk] = *(const sh8*)(Bb + (wn*64 + n*16 + lc)*128 + ((kk*64 + lr*16) ^ swzb));
#pragma unroll
    for (int m = 0; m < 8; ++m)
#pragma unroll
      for (int kk = 0; kk < 2; ++kk)
        a[m][kk] = *(const sh8*)(Ab + (wm*128 + m*16 + lc)*128 + ((kk*64 + lr*16) ^ swzb));
    WAITLGKM0();                  // this wave's reads complete
    BAR();                        // all waves done reading buf[cur]
    if (kt < 15) STAGE(cur ^ 1, kt + 1);   // prefetch next tile; lands during MFMA
    __builtin_amdgcn_s_setprio(1);
#pragma unroll
    for (int m = 0; m < 8; ++m)
#pragma unroll
      for (int n = 0; n < 4; ++n) {
        acc[m][n] = __builtin_amdgcn_mfma_f32_16x16x32_bf16(a[m][0], b[n][0], acc[m][n], 0, 0, 0);
        acc[m][n] = __builtin_amdgcn_mfma_f32_16x16x32_bf16(a[m][1], b[n][1], acc[m][n], 0, 0, 0);
      }
    __builtin_amdgcn_s_setprio(0);
  }
#undef STAGE

  // ---- epilogue: gather xg/dsts into aliased LDS (staging is dead now) ----
  {
    int e = tid >> 1, half = tid & 1;
    int ge = e0 + e;
    float4 v = make_float4(0.f, 0.f, 0.f, 0.f);
    if (ge < E_EDGES) v = *(const float4*)(xin + (size_t)src[ge]*32 + tile_n*8 + half*4);
    *(float4*)&xg[e][half*4] = v;
    if (tid < 256) dsts[tid] = (e0 + tid < E_EDGES) ? dst[e0 + tid] : -1;
  }
  float b2c[4];
#pragma unroll
  for (int n = 0; n < 4; ++n) b2c[n] = b2[n0 + wn*64 + n*16 + lc];
  WAITLGKM0();
  BAR();

  // partial msg: wave covers di = {2wn, 2wn+1}; o = lc (n even) / lc+16 (n odd)
  if ((wn & 1) == 0) {
    float* mb = (wn == 0) ? msgA : msgB;
#pragma unroll
    for (int m = 0; m < 8; ++m)
#pragma unroll
      for (int r = 0; r < 4; ++r) {
        int e = wm*128 + m*16 + lr*4 + r;
        float x0 = xg[e][2*wn], x1 = xg[e][2*wn + 1];
        mb[e*33 + lc]      = (acc[m][0][r] + b2c[0])*x0 + (acc[m][2][r] + b2c[2])*x1;
        mb[e*33 + lc + 16] = (acc[m][1][r] + b2c[1])*x0 + (acc[m][3][r] + b2c[3])*x1;
      }
  }
  BAR();
  if ((wn & 1) == 1) {
    float* mb = (wn == 1) ? msgA : msgB;
#pragma unroll
    for (int m = 0; m < 8; ++m)
#pragma unroll
      for (int r = 0; r < 4; ++r) {
        int e = wm*128 + m*16 + lr*4 + r;
        float x0 = xg[e][2*wn], x1 = xg[e][2*wn + 1];
        mb[e*33 + lc]      += (acc[m][0][r] + b2c[0])*x0 + (acc[m][2][r] + b2c[2])*x1;
        mb[e*33 + lc + 16] += (acc[m][1][r] + b2c[1])*x0 + (acc[m][3][r] + b2c[3])*x1;
      }
  }
  BAR();
  for (int t = tid; t < 256*32; t += 512) {
    int e = t >> 5, o = t & 31;
    int dn = dsts[e];
    if (dn >= 0) atomicAdd(&agg[(size_t)dn*32 + o], msgA[e*33 + o] + msgB[e*33 + o]);
  }
}

// ---- node update: out = relu(agg/max(cnt,1) + x@root + bias) ----
__global__ void node_update_kernel(const float* __restrict__ agg, const float* __restrict__ cnt,
                                   const float* __restrict__ xin, const float* __restrict__ root,
                                   const float* __restrict__ bias, float* __restrict__ outp) {
  int t = blockIdx.x*256 + threadIdx.x;
  if (t >= N_NODES*32) return;
  int n = t >> 5, i = t & 31;
  const float* xr = xin + (size_t)n*32;
  float s = bias[i];
#pragma unroll
  for (int j = 0; j < 32; ++j) s += xr[j]*root[j*32 + i];
  float c = cnt[n]; c = c > 1.f ? c : 1.f;
  float v = agg[t]/c + s;
  outp[t] = fmaxf(v, 0.f);
}

// ---- final: out = h @ lin_w + lin_b ----
__global__ void final_linear_kernel(const float* __restrict__ h, const float* __restrict__ lw,
                                    const float* __restrict__ lb, float* __restrict__ out) {
  int t = blockIdx.x*256 + threadIdx.x;
  if (t >= N_NODES*10) return;
  int n = t / 10, k = t % 10;
  const float* hr = h + (size_t)n*32;
  float s = lb[k];
#pragma unroll
  for (int i = 0; i < 32; ++i) s += hr[i]*lw[i*10 + k];
  out[t] = s;
}

extern "C" void kernel_launch(void* const* d_in, const int* in_sizes, int n_in,
                              void* d_out, int out_size, void* d_ws, size_t ws_size,
                              hipStream_t stream) {
  const float* x     = (const float*)d_in[0];
  const int*   ei    = (const int*)d_in[1];
  const float* ea    = (const float*)d_in[2];
  const float* e1w1  = (const float*)d_in[3];
  const float* e1b1  = (const float*)d_in[4];
  const float* e1w2  = (const float*)d_in[5];
  const float* e1b2  = (const float*)d_in[6];
  const float* root1 = (const float*)d_in[7];
  const float* bias1 = (const float*)d_in[8];
  const float* e2w1  = (const float*)d_in[9];
  const float* e2b1  = (const float*)d_in[10];
  const float* e2w2  = (const float*)d_in[11];
  const float* e2b2  = (const float*)d_in[12];
  const float* root2 = (const float*)d_in[13];
  const float* bias2 = (const float*)d_in[14];
  const float* linw  = (const float*)d_in[15];
  const float* linb  = (const float*)d_in[16];
  const int* srcp = ei;
  const int* dstp = ei + E_EDGES;

  char* ws = (char*)d_ws;
  size_t off = 0;
  auto alloc = [&](size_t bytes) { void* p = ws + off; off += (bytes + 255) & ~(size_t)255; return p; };
  unsigned short* h1buf = (unsigned short*)alloc((size_t)E_PAD*1024*2);   // 205 MB
  unsigned short* w2t   = (unsigned short*)alloc((size_t)1024*1024*2);
  float* agg  = (float*)alloc((size_t)N_NODES*32*4);
  float* cnt  = (float*)alloc((size_t)N_NODES*4);
  float* out1 = (float*)alloc((size_t)N_NODES*32*4);
  float* hbuf = (float*)alloc((size_t)N_NODES*32*4);
  (void)ws_size; (void)n_in; (void)in_sizes; (void)out_size;

  hipMemsetAsync(agg, 0, (size_t)N_NODES*32*4, stream);
  hipMemsetAsync(cnt, 0, (size_t)N_NODES*4, stream);
  count_kernel<<<(E_EDGES + 255)/256, 256, 0, stream>>>(dstp, cnt);

  const int gemm_grid = (E_PAD/256) * 4;   // 391 * 4 = 1564

  // ---- layer 1 ----
  transpose_w2_kernel<<<1024, 256, 0, stream>>>(e1w2, w2t);
  edge_mlp1_kernel<<<E_PAD/8, 256, 0, stream>>>(ea, e1w1, e1b1, h1buf);
  gemm_scatter_kernel<<<gemm_grid, 512, 0, stream>>>(h1buf, w2t, e1b2, x, srcp, dstp, agg);
  node_update_kernel<<<(N_NODES*32 + 255)/256, 256, 0, stream>>>(agg, cnt, x, root1, bias1, out1);

  // ---- layer 2 ----
  hipMemsetAsync(agg, 0, (size_t)N_NODES*32*4, stream);
  transpose_w2_kernel<<<1024, 256, 0, stream>>>(e2w2, w2t);
  edge_mlp1_kernel<<<E_PAD/8, 256, 0, stream>>>(ea, e2w1, e2b1, h1buf);
  gemm_scatter_kernel<<<gemm_grid, 512, 0, stream>>>(h1buf, w2t, e2b2, out1, srcp, dstp, agg);
  node_update_kernel<<<(N_NODES*32 + 255)/256, 256, 0, stream>>>(agg, cnt, out1, root2, bias2, hbuf);

  final_linear_kernel<<<(N_NODES*10 + 255)/256, 256, 0, stream>>>(hbuf, linw, linb, (float*)d_out);
}

// Round 4
// 639.667 us; speedup vs baseline: 1.2196x; 1.2196x over previous
//
#include <hip/hip_runtime.h>

typedef __attribute__((ext_vector_type(8))) short sh8;       // 8 bf16 (4 VGPRs)
typedef __attribute__((ext_vector_type(4))) float f32x4;

#define E_EDGES 100000
#define E_PAD   100096   // 782 * 128
#define N_NODES 20000

__device__ __forceinline__ unsigned short f2bf(float f) {
  union { float f; unsigned int u; } v; v.f = f;
  unsigned int r = v.u + 0x7FFFu + ((v.u >> 16) & 1u);   // RNE
  return (unsigned short)(r >> 16);
}

__device__ __forceinline__ void async16(const void* g, void* l) {
  __builtin_amdgcn_global_load_lds((const __attribute__((address_space(1))) unsigned int*)g,
                                   (__attribute__((address_space(3))) unsigned int*)l,
                                   16, 0, 0);
}

// ---- w2 (f32 [1024][1024] k-major) -> w2t (bf16 [n][k]) ----
__global__ void transpose_w2_kernel(const float* __restrict__ w2, unsigned short* __restrict__ w2t) {
  __shared__ float tile[32][33];
  int b = blockIdx.x;                 // 32x32 tiles
  int bx = b & 31, by = b >> 5;
  int lx = threadIdx.x & 31, ly = threadIdx.x >> 5;   // 32 x 8
#pragma unroll
  for (int j = 0; j < 4; ++j)
    tile[ly + j*8][lx] = w2[(by*32 + ly + j*8)*1024 + bx*32 + lx];
  __syncthreads();
#pragma unroll
  for (int j = 0; j < 4; ++j)
    w2t[(size_t)(bx*32 + ly + j*8)*1024 + by*32 + lx] = f2bf(tile[lx][ly + j*8]);
}

// ---- h1 = relu(ea @ w1 + b1) -> bf16 [E_PAD][1024]; 8 edges per block ----
__global__ __launch_bounds__(256)
void edge_mlp1_kernel(const float* __restrict__ ea, const float* __restrict__ w1,
                      const float* __restrict__ b1, unsigned short* __restrict__ h1) {
  __shared__ float eas[8][16];
  const int tid = threadIdx.x;
  const int e0 = blockIdx.x * 8;
  if (tid < 128) {
    int g = tid >> 4, d = tid & 15;
    int ge = e0 + g;
    eas[g][d] = (ge < E_EDGES) ? ea[(size_t)ge*16 + d] : 0.f;
  }
  __syncthreads();
  const int c0 = tid * 4;
  float4 bb = *(const float4*)(b1 + c0);
  float4 acc[8];
#pragma unroll
  for (int g = 0; g < 8; ++g) acc[g] = bb;
#pragma unroll
  for (int d = 0; d < 16; ++d) {
    float4 w = *(const float4*)(w1 + (size_t)d*1024 + c0);
#pragma unroll
    for (int g = 0; g < 8; ++g) {
      float ev = eas[g][d];
      acc[g].x += ev*w.x; acc[g].y += ev*w.y; acc[g].z += ev*w.z; acc[g].w += ev*w.w;
    }
  }
#pragma unroll
  for (int g = 0; g < 8; ++g) {
    ushort4 o;
    if (e0 + g < E_EDGES) {
      o.x = f2bf(fmaxf(acc[g].x, 0.f)); o.y = f2bf(fmaxf(acc[g].y, 0.f));
      o.z = f2bf(fmaxf(acc[g].z, 0.f)); o.w = f2bf(fmaxf(acc[g].w, 0.f));
    } else {
      o.x = o.y = o.z = o.w = 0;
    }
    *(ushort4*)(h1 + (size_t)(e0 + g)*1024 + c0) = o;
  }
}

// ---- cnt[dst] += 1 ----
__global__ void count_kernel(const int* __restrict__ dst, float* __restrict__ cnt) {
  int t = blockIdx.x*256 + threadIdx.x;
  if (t < E_EDGES) atomicAdd(&cnt[dst[t]], 1.0f);
}

// ---- big GEMM [E,1024]x[1024,1024] fused with per-edge msg contraction + scatter ----
// R2 structure (128^2 tile, 4 waves, __syncthreads loop, 4 blocks/CU) +
// both-sides XOR swizzle (T2): stage source col ^= rj, read byte ^= (row&7)<<4.
__global__ __launch_bounds__(256, 4)
void gemm_scatter_kernel(const unsigned short* __restrict__ h1,
                         const unsigned short* __restrict__ w2t,
                         const float* __restrict__ b2,
                         const float* __restrict__ xin,
                         const int* __restrict__ src,
                         const int* __restrict__ dst,
                         float* __restrict__ agg) {
  // Als/Bls (K-loop) union msgbuf (epilogue only) — separated by __syncthreads
  __shared__ __align__(16) unsigned char smem[32768];
  unsigned short* Als = (unsigned short*)smem;            // [128][64] = 16384 B (swizzled)
  unsigned short* Bls = (unsigned short*)(smem + 16384);  // [128][64] = 16384 B (swizzled)
  float* msgbuf = (float*)smem;                           // [128][33] = 16896 B (epilogue)
  __shared__ __align__(16) float xg[128][4];
  __shared__ int dsts[128];

  const int tid  = threadIdx.x;
  const int wave = tid >> 6, lane = tid & 63;
  const int wm = wave >> 1, wn = wave & 1;               // 2x2 waves, 64x64 each
  const int lr = lane >> 4, lc = lane & 15;
  // XCD-bijective swizzle: grid 6256 = 8 XCD * 782; keep one A-panel's 8
  // n-tiles concurrent on ONE XCD for L2 reuse.
  const int logical = (blockIdx.x & 7) * 782 + (blockIdx.x >> 3);
  const int tile_m = logical >> 3, tile_n = logical & 7;
  const int e0 = tile_m * 128, n0 = tile_n * 128;

  if (tid < 128) {                                       // gather x[src] (4 i's of this col tile)
    int ge = e0 + tid;
    float4 v = make_float4(0.f, 0.f, 0.f, 0.f);
    if (ge < E_EDGES) {
      int s = src[ge];
      v = *(const float4*)(xin + (size_t)s*32 + tile_n*4);
    }
    *(float4*)xg[tid] = v;
  } else {
    int e = tid - 128;
    int ge = e0 + e;
    dsts[e] = (ge < E_EDGES) ? dst[ge] : -1;
  }

  f32x4 acc[4][4];
#pragma unroll
  for (int i = 0; i < 4; ++i)
#pragma unroll
    for (int j = 0; j < 4; ++j) acc[i][j] = (f32x4){0.f,0.f,0.f,0.f};

  const unsigned short* Ag = h1  + (size_t)e0*1024;
  const unsigned short* Bg = w2t + (size_t)n0*1024;
  const int rj     = lane >> 3;                          // row within 8-row group
  const int srow   = wave*32 + rj;                       // + j*8
  const int scol   = 8*((lane & 7) ^ rj);                // pre-swizzled source col
  const int swzb   = (lc & 7) << 4;                      // read-side byte XOR

  for (int kt = 0; kt < 16; ++kt) {
    const int k0 = kt * 64;
    __syncthreads();
#pragma unroll
    for (int j = 0; j < 4; ++j) {
      async16(Ag + (size_t)(srow + j*8)*1024 + k0 + scol, &Als[wave*2048 + j*512]);
      async16(Bg + (size_t)(srow + j*8)*1024 + k0 + scol, &Bls[wave*2048 + j*512]);
    }
    __syncthreads();
#pragma unroll
    for (int kk = 0; kk < 2; ++kk) {
      sh8 av[4], bv[4];
#pragma unroll
      for (int mi = 0; mi < 4; ++mi)
        av[mi] = *(const sh8*)((const char*)Als + (wm*64 + mi*16 + lc)*128 + ((kk*64 + lr*16) ^ swzb));
#pragma unroll
      for (int ni = 0; ni < 4; ++ni)
        bv[ni] = *(const sh8*)((const char*)Bls + (wn*64 + ni*16 + lc)*128 + ((kk*64 + lr*16) ^ swzb));
#pragma unroll
      for (int mi = 0; mi < 4; ++mi)
#pragma unroll
        for (int ni = 0; ni < 4; ++ni)
          acc[mi][ni] = __builtin_amdgcn_mfma_f32_16x16x32_bf16(av[mi], bv[ni], acc[mi][ni], 0, 0, 0);
    }
  }

  // epilogue: h2 = acc + b2;  partial_msg[e][o] = sum_di xg[e][di] * h2[e][di*32+o]
  float b2c[4];
#pragma unroll
  for (int ni = 0; ni < 4; ++ni) b2c[ni] = b2[n0 + wn*64 + ni*16 + lc];

  float ms0[4][4], ms1[4][4];
#pragma unroll
  for (int mi = 0; mi < 4; ++mi)
#pragma unroll
    for (int r = 0; r < 4; ++r) {
      int e = wm*64 + mi*16 + lr*4 + r;
      float x0 = xg[e][2*wn], x1 = xg[e][2*wn + 1];
      ms0[mi][r] = (acc[mi][0][r] + b2c[0])*x0 + (acc[mi][2][r] + b2c[2])*x1;   // o = lc
      ms1[mi][r] = (acc[mi][1][r] + b2c[1])*x0 + (acc[mi][3][r] + b2c[3])*x1;   // o = lc+16
    }

  __syncthreads();   // K-loop LDS dead from here; msgbuf aliases it
  if (wn == 0) {
#pragma unroll
    for (int mi = 0; mi < 4; ++mi)
#pragma unroll
      for (int r = 0; r < 4; ++r) {
        int e = wm*64 + mi*16 + lr*4 + r;
        msgbuf[e*33 + lc]      = ms0[mi][r];
        msgbuf[e*33 + lc + 16] = ms1[mi][r];
      }
  }
  __syncthreads();
  if (wn == 1) {
#pragma unroll
    for (int mi = 0; mi < 4; ++mi)
#pragma unroll
      for (int r = 0; r < 4; ++r) {
        int e = wm*64 + mi*16 + lr*4 + r;
        msgbuf[e*33 + lc]      += ms0[mi][r];
        msgbuf[e*33 + lc + 16] += ms1[mi][r];
      }
  }
  __syncthreads();
  for (int t = tid; t < 128*32; t += 256) {
    int e = t >> 5, o = t & 31;
    int dn = dsts[e];
    if (dn >= 0) atomicAdd(&agg[(size_t)dn*32 + o], msgbuf[e*33 + o]);
  }
}

// ---- node update: out = relu(agg/max(cnt,1) + x@root + bias) ----
__global__ void node_update_kernel(const float* __restrict__ agg, const float* __restrict__ cnt,
                                   const float* __restrict__ xin, const float* __restrict__ root,
                                   const float* __restrict__ bias, float* __restrict__ outp) {
  int t = blockIdx.x*256 + threadIdx.x;
  if (t >= N_NODES*32) return;
  int n = t >> 5, i = t & 31;
  const float* xr = xin + (size_t)n*32;
  float s = bias[i];
#pragma unroll
  for (int j = 0; j < 32; ++j) s += xr[j]*root[j*32 + i];
  float c = cnt[n]; c = c > 1.f ? c : 1.f;
  float v = agg[t]/c + s;
  outp[t] = fmaxf(v, 0.f);
}

// ---- final: out = h @ lin_w + lin_b ----
__global__ void final_linear_kernel(const float* __restrict__ h, const float* __restrict__ lw,
                                    const float* __restrict__ lb, float* __restrict__ out) {
  int t = blockIdx.x*256 + threadIdx.x;
  if (t >= N_NODES*10) return;
  int n = t / 10, k = t % 10;
  const float* hr = h + (size_t)n*32;
  float s = lb[k];
#pragma unroll
  for (int i = 0; i < 32; ++i) s += hr[i]*lw[i*10 + k];
  out[t] = s;
}

extern "C" void kernel_launch(void* const* d_in, const int* in_sizes, int n_in,
                              void* d_out, int out_size, void* d_ws, size_t ws_size,
                              hipStream_t stream) {
  const float* x     = (const float*)d_in[0];
  const int*   ei    = (const int*)d_in[1];
  const float* ea    = (const float*)d_in[2];
  const float* e1w1  = (const float*)d_in[3];
  const float* e1b1  = (const float*)d_in[4];
  const float* e1w2  = (const float*)d_in[5];
  const float* e1b2  = (const float*)d_in[6];
  const float* root1 = (const float*)d_in[7];
  const float* bias1 = (const float*)d_in[8];
  const float* e2w1  = (const float*)d_in[9];
  const float* e2b1  = (const float*)d_in[10];
  const float* e2w2  = (const float*)d_in[11];
  const float* e2b2  = (const float*)d_in[12];
  const float* root2 = (const float*)d_in[13];
  const float* bias2 = (const float*)d_in[14];
  const float* linw  = (const float*)d_in[15];
  const float* linb  = (const float*)d_in[16];
  const int* srcp = ei;
  const int* dstp = ei + E_EDGES;

  char* ws = (char*)d_ws;
  size_t off = 0;
  auto alloc = [&](size_t bytes) { void* p = ws + off; off += (bytes + 255) & ~(size_t)255; return p; };
  unsigned short* h1buf = (unsigned short*)alloc((size_t)E_PAD*1024*2);   // 205 MB
  unsigned short* w2t   = (unsigned short*)alloc((size_t)1024*1024*2);
  float* agg  = (float*)alloc((size_t)N_NODES*32*4);
  float* cnt  = (float*)alloc((size_t)N_NODES*4);
  float* out1 = (float*)alloc((size_t)N_NODES*32*4);
  float* hbuf = (float*)alloc((size_t)N_NODES*32*4);
  (void)ws_size; (void)n_in; (void)in_sizes; (void)out_size;

  hipMemsetAsync(agg, 0, (size_t)N_NODES*32*4, stream);
  hipMemsetAsync(cnt, 0, (size_t)N_NODES*4, stream);
  count_kernel<<<(E_EDGES + 255)/256, 256, 0, stream>>>(dstp, cnt);

  // ---- layer 1 ----
  transpose_w2_kernel<<<1024, 256, 0, stream>>>(e1w2, w2t);
  edge_mlp1_kernel<<<E_PAD/8, 256, 0, stream>>>(ea, e1w1, e1b1, h1buf);
  gemm_scatter_kernel<<<(E_PAD/128)*8, 256, 0, stream>>>(h1buf, w2t, e1b2, x, srcp, dstp, agg);
  node_update_kernel<<<(N_NODES*32 + 255)/256, 256, 0, stream>>>(agg, cnt, x, root1, bias1, out1);

  // ---- layer 2 ----
  hipMemsetAsync(agg, 0, (size_t)N_NODES*32*4, stream);
  transpose_w2_kernel<<<1024, 256, 0, stream>>>(e2w2, w2t);
  edge_mlp1_kernel<<<E_PAD/8, 256, 0, stream>>>(ea, e2w1, e2b1, h1buf);
  gemm_scatter_kernel<<<(E_PAD/128)*8, 256, 0, stream>>>(h1buf, w2t, e2b2, out1, srcp, dstp, agg);
  node_update_kernel<<<(N_NODES*32 + 255)/256, 256, 0, stream>>>(agg, cnt, out1, root2, bias2, hbuf);

  final_linear_kernel<<<(N_NODES*10 + 255)/256, 256, 0, stream>>>(hbuf, linw, linb, (float*)d_out);
}